// Round 4
// baseline (160.797 us; speedup 1.0000x reference)
//
#include <hip/hip_runtime.h>
#include <hip/hip_bf16.h>
#include <stdint.h>

#define NPTS 81920
#define CIN  64
#define COUT 128
#define BATCH 4
#define KNB  10
#define NT   128      // n-tile per block

typedef __attribute__((ext_vector_type(8)))  short bf16x8;
typedef __attribute__((ext_vector_type(16))) float f32x16;

static __device__ __forceinline__ unsigned short f2bf(float f) {
    unsigned int u = __float_as_uint(f);
    u += 0x7fffu + ((u >> 16) & 1u);      // RNE, finite inputs
    return (unsigned short)(u >> 16);
}

static __device__ __forceinline__ void gload16(const void* g, void* l) {
    __builtin_amdgcn_global_load_lds(
        (const __attribute__((address_space(1))) unsigned int*)g,
        (__attribute__((address_space(3))) unsigned int*)l, 16, 0, 0);
}

// ---------------------------------------------------------------------------
// Kernel 1: x (B, CIN, N) f32  ->  xT (N, B, CIN) bf16
//   one gather row per point = 4 batches x 128 B = 512 B contiguous
// ---------------------------------------------------------------------------
__global__ __launch_bounds__(256) void k_transpose(const float* __restrict__ x,
                                                   unsigned short* __restrict__ xT) {
    const int m = blockIdx.x * 256 + threadIdx.x;
    const int b = blockIdx.y;
    const float* xb = x + (size_t)b * CIN * NPTS + m;

    unsigned int v[CIN / 2];
    #pragma unroll
    for (int i = 0; i < CIN / 2; ++i) {
        float f0 = xb[(size_t)(2 * i) * NPTS];       // coalesced across lanes
        float f1 = xb[(size_t)(2 * i + 1) * NPTS];
        v[i] = (unsigned int)f2bf(f0) | ((unsigned int)f2bf(f1) << 16);
    }
    uint4* dst = (uint4*)(xT + ((size_t)m * BATCH + b) * CIN);
    #pragma unroll
    for (int i = 0; i < 8; ++i) {
        uint4 w; w.x = v[4*i]; w.y = v[4*i+1]; w.z = v[4*i+2]; w.w = v[4*i+3];
        dst[i] = w;                                   // 128 B contiguous per lane
    }
}

// ---------------------------------------------------------------------------
// Kernel 2: W (COUT, CIN, KNB) f32 -> Wb bf16 in 32x32x16 A-fragment order:
//   e = ((sg*4 + f)*64 + lane)*8 + j   (sg = 0..39 ksteps of 16, f = o-frag)
//   o = 32*f + (lane&31);  k_local = 8*(lane>>5)+j;  ck = sg*16 + k_local;
//   kn = ck>>6; c = ck&63;  value = W[(o*CIN + c)*KNB + kn]
// ---------------------------------------------------------------------------
__global__ __launch_bounds__(256) void k_wconv(const float* __restrict__ W,
                                               unsigned short* __restrict__ Wb) {
    const int e  = blockIdx.x * 256 + threadIdx.x;   // 0 .. 81919
    const int j  = e & 7;
    const int l  = (e >> 3) & 63;
    const int f  = (e >> 9) & 3;
    const int sg = e >> 11;                          // 0 .. 39
    const int o  = 32 * f + (l & 31);
    const int ck = sg * 16 + 8 * (l >> 5) + j;
    const int kn = ck >> 6;
    const int c  = ck & 63;
    Wb[e] = f2bf(W[(o * CIN + c) * KNB + kn]);
}

// ---------------------------------------------------------------------------
// Main: block = 8 waves = 4 o-frags(32) x 2 n-halves(64); n-tile 128;
// batch-pair bz = grid.y. mfma_32x32x16. LDS chunk-major:
//   smem[buf][chunk][row][16B], chunk = bb*8 + ks*2 + halfwave (16 chunks),
//   row = n-local (128). ds_read_b128 = contiguous 512 B per half-wave
//   (conflict-free); global_load_lds dest linear (1024 B per inst).
// ---------------------------------------------------------------------------
__global__ __launch_bounds__(512, 4) void k_main(const unsigned short* __restrict__ xT,
                                                 const unsigned short* __restrict__ Wb,
                                                 const float* __restrict__ bias,
                                                 const int* __restrict__ idx,
                                                 float* __restrict__ out) {
    __shared__ char smem[2][32 * 1024];

    const int t    = threadIdx.x;
    const int lane = t & 63;
    const int wv   = t >> 6;                 // 0..7
    const int ow   = wv & 3;                 // o-frag (32 o)
    const int nh   = wv >> 2;                // n-half (64 n)
    const int hw   = lane >> 5;              // half-wave
    const int l31  = lane & 31;
    const int bz   = blockIdx.y;             // batch pair
    const int nb   = blockIdx.x * NT;

    const char* xb = (const char*)xT + bz * 256;   // batch-pair base within row
    const bf16x8* wbase = (const bf16x8*)Wb;

    f32x16 acc[2][2];                        // [nf][bb]
    #pragma unroll
    for (int nf = 0; nf < 2; ++nf)
        #pragma unroll
        for (int bb = 0; bb < 2; ++bb)
            #pragma unroll
            for (int r = 0; r < 16; ++r) acc[nf][bb][r] = 0.f;

    // Stage neighbor kk into smem[buf]: 32 KB, 4 gload16/thread.
    //   seg = wv*4+i: chunk = seg>>1 (= wv*2 + (i>>1)), rhalf = seg&1;
    //   lane writes LDS chunk*2048 + rhalf*1024 + lane*16  (row = rhalf*64+lane)
    //   source: xT row idx[nb+row][kk], byte (chunk>>3)*128 + (chunk&7)*16
    #define STAGE(kk, buf)                                                      \
        {                                                                       \
            const int r0 = idx[(nb + lane) * KNB + (kk)];                       \
            const int r1 = idx[(nb + 64 + lane) * KNB + (kk)];                  \
            _Pragma("unroll")                                                   \
            for (int i = 0; i < 4; ++i) {                                       \
                const int chunk = (wv << 1) + (i >> 1);                         \
                const int rh    = i & 1;                                        \
                const int r     = rh ? r1 : r0;                                 \
                const char* src = xb + (size_t)r * 512 +                        \
                                  ((chunk >> 3) << 7) + ((chunk & 7) << 4);     \
                gload16(src, &smem[buf][(chunk << 11) + (rh << 10)]);           \
            }                                                                   \
        }

    bf16x8 a[4], an[4];
    STAGE(0, 0);
    #pragma unroll
    for (int ks = 0; ks < 4; ++ks)
        a[ks] = wbase[((0 * 4 + ks) * 4 + ow) * 64 + lane];
    __syncthreads();                          // stage(0) landed (vmcnt drain)

    #pragma unroll
    for (int k = 0; k < KNB; ++k) {
        if (k + 1 < KNB) {
            STAGE(k + 1, (k + 1) & 1);        // async into other buffer
            #pragma unroll
            for (int ks = 0; ks < 4; ++ks)
                an[ks] = wbase[(((k + 1) * 4 + ks) * 4 + ow) * 64 + lane];
        }
        const char* sb = smem[k & 1];
        #pragma unroll
        for (int ks = 0; ks < 4; ++ks) {
            #pragma unroll
            for (int nf = 0; nf < 2; ++nf) {
                const int row = nh * 64 + nf * 32 + l31;
                #pragma unroll
                for (int bb = 0; bb < 2; ++bb) {
                    const int chunk = bb * 8 + ks * 2 + hw;
                    const bf16x8 bf = *(const bf16x8*)(sb + chunk * 2048 + row * 16);
                    acc[nf][bb] = __builtin_amdgcn_mfma_f32_32x32x16_bf16(
                        a[ks], bf, acc[nf][bb], 0, 0, 0);
                }
            }
        }
        __syncthreads();                      // stage(k+1) landed + WAR fence
        #pragma unroll
        for (int ks = 0; ks < 4; ++ks) a[ks] = an[ks];
    }
    #undef STAGE

    // Epilogue: o = 32*ow + (r&3) + 8*(r>>2) + 4*hw; n = nb + nh*64 + nf*32 + l31.
    float bv[16];
    #pragma unroll
    for (int r = 0; r < 16; ++r)
        bv[r] = bias[32 * ow + (r & 3) + 8 * (r >> 2) + 4 * hw];

    #pragma unroll
    for (int nf = 0; nf < 2; ++nf) {
        const int n = nb + nh * 64 + nf * 32 + l31;
        #pragma unroll
        for (int bb = 0; bb < 2; ++bb) {
            const int b = bz * 2 + bb;
            #pragma unroll
            for (int r = 0; r < 16; ++r) {
                const int o = 32 * ow + (r & 3) + 8 * (r >> 2) + 4 * hw;
                out[(size_t)(b * COUT + o) * NPTS + n] = acc[nf][bb][r] + bv[r];
            }
        }
    }
}

// ---------------------------------------------------------------------------
extern "C" void kernel_launch(void* const* d_in, const int* in_sizes, int n_in,
                              void* d_out, int out_size, void* d_ws, size_t ws_size,
                              hipStream_t stream) {
    const float* x    = (const float*)d_in[0];
    const int*   idx  = (const int*)d_in[1];
    const float* W    = (const float*)d_in[2];
    const float* bias = (const float*)d_in[3];
    float* out = (float*)d_out;

    // Workspace layout: xT bf16 (N*B*CIN*2 = 41.94 MB), then Wb bf16 (160 KB).
    unsigned short* xT = (unsigned short*)d_ws;
    unsigned short* Wb = (unsigned short*)((char*)d_ws + (size_t)BATCH * NPTS * CIN * 2);

    k_transpose<<<dim3(NPTS / 256, BATCH), 256, 0, stream>>>(x, xT);
    k_wconv<<<dim3((COUT * KNB * CIN) / 256), 256, 0, stream>>>(W, Wb);
    k_main<<<dim3(NPTS / NT, 2), 512, 0, stream>>>(xT, Wb, bias, idx, out);
}

// Round 5
// 159.542 us; speedup vs baseline: 1.0079x; 1.0079x over previous
//
#include <hip/hip_runtime.h>
#include <hip/hip_bf16.h>
#include <stdint.h>

#define NPTS 81920
#define CIN  64
#define COUT 128
#define BATCH 4
#define KNB  10
#define NT   64       // n-rows per block

typedef __attribute__((ext_vector_type(8)))  short bf16x8;
typedef __attribute__((ext_vector_type(16))) float f32x16;

static __device__ __forceinline__ unsigned short f2bf(float f) {
    unsigned int u = __float_as_uint(f);
    u += 0x7fffu + ((u >> 16) & 1u);      // RNE, finite inputs
    return (unsigned short)(u >> 16);
}

static __device__ __forceinline__ void gload16(const void* g, void* l) {
    __builtin_amdgcn_global_load_lds(
        (const __attribute__((address_space(1))) unsigned int*)g,
        (__attribute__((address_space(3))) unsigned int*)l, 16, 0, 0);
}

// ---------------------------------------------------------------------------
// Kernel 1: x (B, CIN, N) f32  ->  xT (N, B, CIN) bf16
//   one gather row per point = 4 batches x 128 B = 512 B contiguous
// ---------------------------------------------------------------------------
__global__ __launch_bounds__(256) void k_transpose(const float* __restrict__ x,
                                                   unsigned short* __restrict__ xT) {
    const int m = blockIdx.x * 256 + threadIdx.x;
    const int b = blockIdx.y;
    const float* xb = x + (size_t)b * CIN * NPTS + m;

    unsigned int v[CIN / 2];
    #pragma unroll
    for (int i = 0; i < CIN / 2; ++i) {
        float f0 = xb[(size_t)(2 * i) * NPTS];       // coalesced across lanes
        float f1 = xb[(size_t)(2 * i + 1) * NPTS];
        v[i] = (unsigned int)f2bf(f0) | ((unsigned int)f2bf(f1) << 16);
    }
    uint4* dst = (uint4*)(xT + ((size_t)m * BATCH + b) * CIN);
    #pragma unroll
    for (int i = 0; i < 8; ++i) {
        uint4 w; w.x = v[4*i]; w.y = v[4*i+1]; w.z = v[4*i+2]; w.w = v[4*i+3];
        dst[i] = w;                                   // 128 B contiguous per lane
    }
}

// ---------------------------------------------------------------------------
// Kernel 2: W (COUT, CIN, KNB) f32 -> Wb bf16 in 32x32x16 A-fragment order:
//   e = ((sg*4 + f)*64 + lane)*8 + j   (sg = 0..39 ksteps of 16, f = o-frag)
//   o = 32*f + (lane&31);  ck = sg*16 + 8*(lane>>5) + j;
//   kn = ck>>6; c = ck&63;  value = W[(o*CIN + c)*KNB + kn]
// ---------------------------------------------------------------------------
__global__ __launch_bounds__(256) void k_wconv(const float* __restrict__ W,
                                               unsigned short* __restrict__ Wb) {
    const int e  = blockIdx.x * 256 + threadIdx.x;   // 0 .. 81919
    const int j  = e & 7;
    const int l  = (e >> 3) & 63;
    const int f  = (e >> 9) & 3;
    const int sg = e >> 11;                          // 0 .. 39
    const int o  = 32 * f + (l & 31);
    const int ck = sg * 16 + 8 * (l >> 5) + j;
    const int kn = ck >> 6;
    const int c  = ck & 63;
    Wb[e] = f2bf(W[(o * CIN + c) * KNB + kn]);
}

// ---------------------------------------------------------------------------
// Main: block = 4 waves (256 thr), NT=64 rows, ALL 4 batches.
// Wave wv: of-pair ow2 = wv&1 (o in {64*ow2 .. 64*ow2+63}), b-pair bq = wv>>1.
// Per wave: 2 of x 2 nf x 2 b = 8 f32x16 acc. B-frag reused across the 2 of
// MFMAs -> LDS amplification 2x. mfma_32x32x16.
// LDS: smem[buf][64 rows][512 B] row-major; staged row-contiguous with
// 16B-granule XOR source pre-swizzle; reads hit 4-way bank conflict (floor
// for b128 at 512B row stride) - accepted, see round-5 analysis.
// ---------------------------------------------------------------------------
__global__ __launch_bounds__(256, 2) void k_main(const unsigned short* __restrict__ xT,
                                                 const unsigned short* __restrict__ Wb,
                                                 const float* __restrict__ bias,
                                                 const int* __restrict__ idx,
                                                 float* __restrict__ out) {
    __shared__ char smem[2][NT * 512];

    const int t    = threadIdx.x;
    const int lane = t & 63;
    const int wv   = t >> 6;                 // 0..3
    const int ow2  = wv & 1;                 // of-pair
    const int bq   = wv >> 1;                // batch-pair
    const int hw   = lane >> 5;              // half-wave
    const int l31  = lane & 31;
    const int nb   = blockIdx.x * NT;

    const char* xb = (const char*)xT;
    const bf16x8* wbase = (const bf16x8*)Wb;

    f32x16 acc[2][2][2];                     // [p(of)][nf][bb]
    #pragma unroll
    for (int p = 0; p < 2; ++p)
        #pragma unroll
        for (int nf = 0; nf < 2; ++nf)
            #pragma unroll
            for (int bb = 0; bb < 2; ++bb)
                #pragma unroll
                for (int r = 0; r < 16; ++r) acc[p][nf][bb][r] = 0.f;

    // Stage neighbor kk: 64 rows x 512 B = 32 KB. 8 insts/thread; inst
    // seg = wv*8+i covers rows {2seg, 2seg+1}; lane reads its row's 512 B
    // contiguously (32 lanes/row). Source chunk pre-swizzled by row&7 so
    // linear LDS dest + XOR'd read line up (rule #21).
    #define STAGE(kk, buf)                                                      \
        {                                                                       \
            _Pragma("unroll")                                                   \
            for (int i = 0; i < 8; ++i) {                                       \
                const int seg = (wv << 3) + i;                                  \
                const int row = (seg << 1) + (lane >> 5);                       \
                const int r   = idx[(nb + row) * KNB + (kk)];                   \
                const char* src = xb + (size_t)r * 512 +                        \
                                  ((((lane & 31) << 4)) ^ ((row & 7) << 4));    \
                gload16(src, &smem[buf][seg << 10]);                            \
            }                                                                   \
        }

    STAGE(0, 0);
    __syncthreads();                          // stage(0) landed (vmcnt drain)

    #pragma unroll
    for (int k = 0; k < KNB; ++k) {
        if (k + 1 < KNB) STAGE(k + 1, (k + 1) & 1);   // async into other buffer

        // A-fragments for this neighbor: 2 of x 4 ks (Wb is L2-hot, 160 KB).
        bf16x8 a[2][4];
        #pragma unroll
        for (int p = 0; p < 2; ++p)
            #pragma unroll
            for (int ks = 0; ks < 4; ++ks)
                a[p][ks] = wbase[((k * 4 + ks) * 4 + (ow2 * 2 + p)) * 64 + lane];

        const char* sb = smem[k & 1];
        #pragma unroll
        for (int ks = 0; ks < 4; ++ks) {
            #pragma unroll
            for (int nf = 0; nf < 2; ++nf) {
                const int row = nf * 32 + l31;
                #pragma unroll
                for (int bb = 0; bb < 2; ++bb) {
                    const int b = bq * 2 + bb;
                    const int g = b * 8 + ks * 2 + hw;          // 16B chunk id
                    const int byte = (g ^ (row & 7)) << 4;
                    const bf16x8 bf = *(const bf16x8*)(sb + row * 512 + byte);
                    #pragma unroll
                    for (int p = 0; p < 2; ++p)
                        acc[p][nf][bb] = __builtin_amdgcn_mfma_f32_32x32x16_bf16(
                            a[p][ks], bf, acc[p][nf][bb], 0, 0, 0);
                }
            }
        }
        __syncthreads();                      // stage(k+1) landed + WAR fence
    }
    #undef STAGE

    // Epilogue: o = 32*(2*ow2+p) + (r&3) + 8*(r>>2) + 4*hw;
    //           n = nb + nf*32 + l31; b = 2*bq + bb.
    #pragma unroll
    for (int p = 0; p < 2; ++p) {
        #pragma unroll
        for (int nf = 0; nf < 2; ++nf) {
            const int n = nb + nf * 32 + l31;
            #pragma unroll
            for (int bb = 0; bb < 2; ++bb) {
                const int b = bq * 2 + bb;
                #pragma unroll
                for (int r = 0; r < 16; ++r) {
                    const int o = 32 * (ow2 * 2 + p) + (r & 3) + 8 * (r >> 2) + 4 * hw;
                    out[(size_t)(b * COUT + o) * NPTS + n] = acc[p][nf][bb][r] + bias[o];
                }
            }
        }
    }
}

// ---------------------------------------------------------------------------
extern "C" void kernel_launch(void* const* d_in, const int* in_sizes, int n_in,
                              void* d_out, int out_size, void* d_ws, size_t ws_size,
                              hipStream_t stream) {
    const float* x    = (const float*)d_in[0];
    const int*   idx  = (const int*)d_in[1];
    const float* W    = (const float*)d_in[2];
    const float* bias = (const float*)d_in[3];
    float* out = (float*)d_out;

    // Workspace layout: xT bf16 (N*B*CIN*2 = 41.94 MB), then Wb bf16 (160 KB).
    unsigned short* xT = (unsigned short*)d_ws;
    unsigned short* Wb = (unsigned short*)((char*)d_ws + (size_t)BATCH * NPTS * CIN * 2);

    k_transpose<<<dim3(NPTS / 256, BATCH), 256, 0, stream>>>(x, xT);
    k_wconv<<<dim3((COUT * KNB * CIN) / 256), 256, 0, stream>>>(W, Wb);
    k_main<<<dim3(NPTS / NT), 256, 0, stream>>>(xT, Wb, bias, idx, out);
}

// Round 6
// 145.202 us; speedup vs baseline: 1.1074x; 1.0988x over previous
//
#include <hip/hip_runtime.h>
#include <hip/hip_bf16.h>
#include <stdint.h>

#define NPTS 81920
#define CIN  64
#define COUT 128
#define BATCH 4
#define KNB  10
#define NT   32       // n-rows per block

typedef __attribute__((ext_vector_type(8)))  short bf16x8;
typedef __attribute__((ext_vector_type(16))) float f32x16;

static __device__ __forceinline__ unsigned short f2bf(float f) {
    unsigned int u = __float_as_uint(f);
    u += 0x7fffu + ((u >> 16) & 1u);      // RNE, finite inputs
    return (unsigned short)(u >> 16);
}

static __device__ __forceinline__ void gload16(const void* g, void* l) {
    __builtin_amdgcn_global_load_lds(
        (const __attribute__((address_space(1))) unsigned int*)g,
        (__attribute__((address_space(3))) unsigned int*)l, 16, 0, 0);
}

// ---------------------------------------------------------------------------
// Kernel 1: x (B, CIN, N) f32  ->  xT (N, B, CIN) bf16
//   one gather row per point = 4 batches x 128 B = 512 B contiguous.
//   x is read once -> nontemporal loads (keep L3 for xT residency).
// ---------------------------------------------------------------------------
__global__ __launch_bounds__(256) void k_transpose(const float* __restrict__ x,
                                                   unsigned short* __restrict__ xT) {
    const int m = blockIdx.x * 256 + threadIdx.x;
    const int b = blockIdx.y;
    const float* xb = x + (size_t)b * CIN * NPTS + m;

    unsigned int v[CIN / 2];
    #pragma unroll
    for (int i = 0; i < CIN / 2; ++i) {
        float f0 = __builtin_nontemporal_load(&xb[(size_t)(2 * i) * NPTS]);
        float f1 = __builtin_nontemporal_load(&xb[(size_t)(2 * i + 1) * NPTS]);
        v[i] = (unsigned int)f2bf(f0) | ((unsigned int)f2bf(f1) << 16);
    }
    uint4* dst = (uint4*)(xT + ((size_t)m * BATCH + b) * CIN);
    #pragma unroll
    for (int i = 0; i < 8; ++i) {
        uint4 w; w.x = v[4*i]; w.y = v[4*i+1]; w.z = v[4*i+2]; w.w = v[4*i+3];
        dst[i] = w;                                   // 128 B contiguous per lane
    }
}

// ---------------------------------------------------------------------------
// Kernel 2: W (COUT, CIN, KNB) f32 -> Wb bf16 in 32x32x16 A-fragment order:
//   e = ((sg*4 + f)*64 + lane)*8 + j   (sg = 0..39 ksteps of 16, f = o-frag)
//   o = 32*f + (lane&31);  ck = sg*16 + 8*(lane>>5) + j;
//   kn = ck>>6; c = ck&63;  value = W[(o*CIN + c)*KNB + kn]
// ---------------------------------------------------------------------------
__global__ __launch_bounds__(256) void k_wconv(const float* __restrict__ W,
                                               unsigned short* __restrict__ Wb) {
    const int e  = blockIdx.x * 256 + threadIdx.x;   // 0 .. 81919
    const int j  = e & 7;
    const int l  = (e >> 3) & 63;
    const int f  = (e >> 9) & 3;
    const int sg = e >> 11;                          // 0 .. 39
    const int o  = 32 * f + (l & 31);
    const int ck = sg * 16 + 8 * (l >> 5) + j;
    const int kn = ck >> 6;
    const int c  = ck & 63;
    Wb[e] = f2bf(W[(o * CIN + c) * KNB + kn]);
}

// ---------------------------------------------------------------------------
// Main: block = 8 waves (512 thr), NT=32 rows, ALL 4 batches in-block.
// Wave wv: op = wv&1 (o-frag pair {2op, 2op+1}), b = wv>>1 (one batch).
// Per wave: acc[p] = 2 x f32x16 = 32 AGPR; B-frag reused across 2 o-frags
// (LDS amplification 2x). mfma_32x32x16.
// LDS: smem[buf][32 rows][512 B]; staged row-contiguous (2 rows / gload16
// inst) with 16B-granule XOR source pre-swizzle (rule #21: linear dest +
// same XOR on read). Reads: accepted 4-way conflict (structural floor).
// out: nontemporal stores (never re-read; keep L3 for the xT gather).
// ---------------------------------------------------------------------------
__global__ __launch_bounds__(512, 4) void k_main(const unsigned short* __restrict__ xT,
                                                 const unsigned short* __restrict__ Wb,
                                                 const float* __restrict__ bias,
                                                 const int* __restrict__ idx,
                                                 float* __restrict__ out) {
    __shared__ char smem[2][NT * 512];

    const int t    = threadIdx.x;
    const int lane = t & 63;
    const int wv   = t >> 6;                 // 0..7
    const int op   = wv & 1;                 // o-pair: frags {2op, 2op+1}
    const int b    = wv >> 1;                // batch 0..3
    const int hw   = lane >> 5;              // half-wave
    const int l31  = lane & 31;
    const int nb   = blockIdx.x * NT;

    const char* xb = (const char*)xT;
    const bf16x8* wbase = (const bf16x8*)Wb;

    // Precompute stage byte-offsets (all statically indexed -> registers).
    // Wave stages rows 4wv .. 4wv+3: inst i covers rows {4wv+2i, 4wv+2i+1},
    // lane's row = 4wv+2i+hw, lane reads source granule (l31 ^ (row&7)).
    int soff[KNB][2];
    #pragma unroll
    for (int k = 0; k < KNB; ++k) {
        #pragma unroll
        for (int i = 0; i < 2; ++i) {
            const int row = (wv << 2) + (i << 1) + hw;
            const int r   = idx[(nb + row) * KNB + k];
            soff[k][i] = r * 512 + ((l31 ^ (row & 7)) << 4);
        }
    }

    f32x16 acc[2];
    #pragma unroll
    for (int p = 0; p < 2; ++p)
        #pragma unroll
        for (int r = 0; r < 16; ++r) acc[p][r] = 0.f;

    #define STAGE(kk, buf)                                                      \
        {                                                                       \
            _Pragma("unroll")                                                   \
            for (int i = 0; i < 2; ++i) {                                       \
                gload16(xb + soff[kk][i],                                       \
                        &smem[buf][(((wv << 2) + (i << 1))) << 9]);             \
            }                                                                   \
        }

    STAGE(0, 0);
    __syncthreads();                          // stage(0) landed (vmcnt drain)

    #pragma unroll
    for (int k = 0; k < KNB; ++k) {
        if (k + 1 < KNB) STAGE(k + 1, (k + 1) & 1);   // overlaps this k's work

        // A-fragments: 2 o-frags x 4 ksteps, 1 KB each from Wb (L1/L2-hot).
        bf16x8 a[2][4];
        #pragma unroll
        for (int p = 0; p < 2; ++p)
            #pragma unroll
            for (int ks = 0; ks < 4; ++ks)
                a[p][ks] = wbase[((k * 4 + ks) * 4 + (op * 2 + p)) * 64 + lane];

        const char* sb = smem[k & 1];
        #pragma unroll
        for (int ks = 0; ks < 4; ++ks) {
            const int g    = b * 8 + ks * 2 + hw;            // true 16B granule
            const int byte = (g ^ (l31 & 7)) << 4;           // XOR-swizzled slot
            const bf16x8 bf = *(const bf16x8*)(sb + l31 * 512 + byte);
            #pragma unroll
            for (int p = 0; p < 2; ++p)
                acc[p] = __builtin_amdgcn_mfma_f32_32x32x16_bf16(
                    a[p][ks], bf, acc[p], 0, 0, 0);
        }
        __syncthreads();                      // stage(k+1) landed + WAR fence
    }
    #undef STAGE

    // Epilogue: o = 32*(2op+p) + (r&3) + 8*(r>>2) + 4*hw; n = nb + l31.
    const int n = nb + l31;
    #pragma unroll
    for (int p = 0; p < 2; ++p) {
        #pragma unroll
        for (int r = 0; r < 16; ++r) {
            const int o = 32 * (op * 2 + p) + (r & 3) + 8 * (r >> 2) + 4 * hw;
            const float v = acc[p][r] + bias[o];
            __builtin_nontemporal_store(v, &out[(size_t)(b * COUT + o) * NPTS + n]);
        }
    }
}

// ---------------------------------------------------------------------------
extern "C" void kernel_launch(void* const* d_in, const int* in_sizes, int n_in,
                              void* d_out, int out_size, void* d_ws, size_t ws_size,
                              hipStream_t stream) {
    const float* x    = (const float*)d_in[0];
    const int*   idx  = (const int*)d_in[1];
    const float* W    = (const float*)d_in[2];
    const float* bias = (const float*)d_in[3];
    float* out = (float*)d_out;

    // Workspace layout: xT bf16 (N*B*CIN*2 = 41.94 MB), then Wb bf16 (160 KB).
    unsigned short* xT = (unsigned short*)d_ws;
    unsigned short* Wb = (unsigned short*)((char*)d_ws + (size_t)BATCH * NPTS * CIN * 2);

    k_transpose<<<dim3(NPTS / 256, BATCH), 256, 0, stream>>>(x, xT);
    k_wconv<<<dim3((COUT * KNB * CIN) / 256), 256, 0, stream>>>(W, Wb);
    k_main<<<dim3(NPTS / NT), 512, 0, stream>>>(xT, Wb, bias, idx, out);
}

// Round 7
// 135.273 us; speedup vs baseline: 1.1887x; 1.0734x over previous
//
#include <hip/hip_runtime.h>
#include <hip/hip_bf16.h>
#include <stdint.h>

#define NPTS 81920
#define CIN  64
#define COUT 128
#define BATCH 4
#define KNB  10
#define NT   32       // n-rows per block

typedef __attribute__((ext_vector_type(8)))  short bf16x8;
typedef __attribute__((ext_vector_type(16))) float f32x16;

static __device__ __forceinline__ unsigned short f2bf(float f) {
    unsigned int u = __float_as_uint(f);
    u += 0x7fffu + ((u >> 16) & 1u);      // RNE, finite inputs
    return (unsigned short)(u >> 16);
}

static __device__ __forceinline__ void gload16(const void* g, void* l) {
    __builtin_amdgcn_global_load_lds(
        (const __attribute__((address_space(1))) unsigned int*)g,
        (__attribute__((address_space(3))) unsigned int*)l, 16, 0, 0);
}

// ---------------------------------------------------------------------------
// Kernel 1: x (B, CIN, N) f32  ->  xT (N, B, CIN) bf16
//   one gather row per point = 4 batches x 128 B = 512 B contiguous.
// ---------------------------------------------------------------------------
__global__ __launch_bounds__(256) void k_transpose(const float* __restrict__ x,
                                                   unsigned short* __restrict__ xT) {
    const int m = blockIdx.x * 256 + threadIdx.x;
    const int b = blockIdx.y;
    const float* xb = x + (size_t)b * CIN * NPTS + m;

    unsigned int v[CIN / 2];
    #pragma unroll
    for (int i = 0; i < CIN / 2; ++i) {
        float f0 = __builtin_nontemporal_load(&xb[(size_t)(2 * i) * NPTS]);
        float f1 = __builtin_nontemporal_load(&xb[(size_t)(2 * i + 1) * NPTS]);
        v[i] = (unsigned int)f2bf(f0) | ((unsigned int)f2bf(f1) << 16);
    }
    uint4* dst = (uint4*)(xT + ((size_t)m * BATCH + b) * CIN);
    #pragma unroll
    for (int i = 0; i < 8; ++i) {
        uint4 w; w.x = v[4*i]; w.y = v[4*i+1]; w.z = v[4*i+2]; w.w = v[4*i+3];
        dst[i] = w;                                   // 128 B contiguous per lane
    }
}

// ---------------------------------------------------------------------------
// Kernel 2: W (COUT, CIN, KNB) f32 -> Wb bf16 in 32x32x16 A-fragment order:
//   e = ((sg*4 + f)*64 + lane)*8 + j   (sg = 0..39 ksteps of 16, f = o-frag)
//   o = 32*f + (lane&31);  ck = sg*16 + 8*(lane>>5) + j;
//   kn = ck>>6; c = ck&63;  value = W[(o*CIN + c)*KNB + kn]
// ---------------------------------------------------------------------------
__global__ __launch_bounds__(256) void k_wconv(const float* __restrict__ W,
                                               unsigned short* __restrict__ Wb) {
    const int e  = blockIdx.x * 256 + threadIdx.x;   // 0 .. 81919
    const int j  = e & 7;
    const int l  = (e >> 3) & 63;
    const int f  = (e >> 9) & 3;
    const int sg = e >> 11;                          // 0 .. 39
    const int o  = 32 * f + (l & 31);
    const int ck = sg * 16 + 8 * (l >> 5) + j;
    const int kn = ck >> 6;
    const int c  = ck & 63;
    Wb[e] = f2bf(W[(o * CIN + c) * KNB + kn]);
}

// ---------------------------------------------------------------------------
// Main: block = 4 waves (256 thr), NT=32 rows, ALL 4 batches in-block.
// Wave wv: op = wv&1 (o-frag pair {2op,2op+1}), bq = wv>>1 (batches {2bq,2bq+1}).
// Per wave: acc[p][bb] = 4 x f32x16 = 64 AGPR; each B-read feeds 2 MFMAs
// (p reuse), each A-frag feeds 2 MFMAs (bb reuse). mfma_32x32x16.
//
// Pipeline (T3/T4): 3 LDS buffers, stage 2 iters ahead via global_load_lds,
// raw s_barrier + counted s_waitcnt vmcnt(4) (only last iter drains to 0).
// vmcnt retires in issue order: at top of iter k the 4 stage(k+1) insts are
// newer than stage(k), so vmcnt(4) proves stage(k) landed; barrier publishes
// to all waves and fences WAR on buf (k+2)%3 (readers of that buf finished
// compute(k-1) before this barrier).
// ---------------------------------------------------------------------------
__global__ __launch_bounds__(256, 3) void k_main(const unsigned short* __restrict__ xT,
                                                 const unsigned short* __restrict__ Wb,
                                                 const float* __restrict__ bias,
                                                 const int* __restrict__ idx,
                                                 float* __restrict__ out) {
    __shared__ char smem[3][NT * 512];

    const int t    = threadIdx.x;
    const int lane = t & 63;
    const int wv   = t >> 6;                 // 0..3
    const int op   = wv & 1;                 // o-pair: frags {2op, 2op+1}
    const int bq   = wv >> 1;                // batch pair {2bq, 2bq+1}
    const int hw   = lane >> 5;              // half-wave
    const int l31  = lane & 31;
    const int nb   = blockIdx.x * NT;

    const char* xb = (const char*)xT;
    const bf16x8* wbase = (const bf16x8*)Wb;

    // Precompute stage byte-offsets (statically indexed -> registers).
    // Wave stages rows 8wv .. 8wv+7: inst i covers rows {8wv+2i, 8wv+2i+1};
    // lane's source row = 8wv+2i+hw, source granule (l31 ^ (row&7)).
    int soff[KNB][4];
    #pragma unroll
    for (int k = 0; k < KNB; ++k) {
        #pragma unroll
        for (int i = 0; i < 4; ++i) {
            const int row = (wv << 3) + (i << 1) + hw;
            const int r   = idx[(nb + row) * KNB + k];
            soff[k][i] = r * 512 + ((l31 ^ (row & 7)) << 4);
        }
    }

    f32x16 acc[2][2];                        // [p][bb]
    #pragma unroll
    for (int p = 0; p < 2; ++p)
        #pragma unroll
        for (int bb = 0; bb < 2; ++bb)
            #pragma unroll
            for (int r = 0; r < 16; ++r) acc[p][bb][r] = 0.f;

    #define STAGE(kk, buf)                                                      \
        {                                                                       \
            _Pragma("unroll")                                                   \
            for (int i = 0; i < 4; ++i) {                                       \
                gload16(xb + soff[kk][i],                                       \
                        &smem[buf][((wv << 3) + (i << 1)) << 9]);               \
            }                                                                   \
        }

    STAGE(0, 0);
    STAGE(1, 1);

    #pragma unroll
    for (int k = 0; k < KNB; ++k) {
        // Counted wait: stage(k) retired (4 newer stage(k+1) insts may fly).
        if (k == KNB - 1) asm volatile("s_waitcnt vmcnt(0)" ::: "memory");
        else              asm volatile("s_waitcnt vmcnt(4)" ::: "memory");
        __builtin_amdgcn_s_barrier();

        if (k + 2 < KNB) STAGE(k + 2, (k + 2) % 3);   // 2-ahead into 3rd buffer

        // A-fragments: 2 o-frags x 4 ksteps from Wb (L1/L2-hot).
        bf16x8 a[2][4];
        #pragma unroll
        for (int p = 0; p < 2; ++p)
            #pragma unroll
            for (int ks = 0; ks < 4; ++ks)
                a[p][ks] = wbase[((k * 4 + ks) * 4 + (op * 2 + p)) * 64 + lane];

        const char* sb = smem[k % 3];
        #pragma unroll
        for (int ks = 0; ks < 4; ++ks) {
            bf16x8 bf[2];
            #pragma unroll
            for (int bb = 0; bb < 2; ++bb) {
                const int g    = (bq * 2 + bb) * 8 + ks * 2 + hw;   // 16B granule
                const int byte = (g ^ (l31 & 7)) << 4;              // swizzled slot
                bf[bb] = *(const bf16x8*)(sb + l31 * 512 + byte);
            }
            #pragma unroll
            for (int p = 0; p < 2; ++p)
                #pragma unroll
                for (int bb = 0; bb < 2; ++bb)
                    acc[p][bb] = __builtin_amdgcn_mfma_f32_32x32x16_bf16(
                        a[p][ks], bf[bb], acc[p][bb], 0, 0, 0);
        }
    }
    #undef STAGE

    // Epilogue: o = 32*(2op+p) + (r&3) + 8*(r>>2) + 4*hw; n = nb + l31;
    //           b = 2bq + bb. Nontemporal (out never re-read).
    const int n = nb + l31;
    #pragma unroll
    for (int p = 0; p < 2; ++p) {
        #pragma unroll
        for (int bb = 0; bb < 2; ++bb) {
            const int b = bq * 2 + bb;
            #pragma unroll
            for (int r = 0; r < 16; ++r) {
                const int o = 32 * (op * 2 + p) + (r & 3) + 8 * (r >> 2) + 4 * hw;
                const float v = acc[p][bb][r] + bias[o];
                __builtin_nontemporal_store(v, &out[(size_t)(b * COUT + o) * NPTS + n]);
            }
        }
    }
}

// ---------------------------------------------------------------------------
extern "C" void kernel_launch(void* const* d_in, const int* in_sizes, int n_in,
                              void* d_out, int out_size, void* d_ws, size_t ws_size,
                              hipStream_t stream) {
    const float* x    = (const float*)d_in[0];
    const int*   idx  = (const int*)d_in[1];
    const float* W    = (const float*)d_in[2];
    const float* bias = (const float*)d_in[3];
    float* out = (float*)d_out;

    // Workspace layout: xT bf16 (N*B*CIN*2 = 41.94 MB), then Wb bf16 (160 KB).
    unsigned short* xT = (unsigned short*)d_ws;
    unsigned short* Wb = (unsigned short*)((char*)d_ws + (size_t)BATCH * NPTS * CIN * 2);

    k_transpose<<<dim3(NPTS / 256, BATCH), 256, 0, stream>>>(x, xT);
    k_wconv<<<dim3((COUT * KNB * CIN) / 256), 256, 0, stream>>>(W, Wb);
    k_main<<<dim3(NPTS / NT), 256, 0, stream>>>(xT, Wb, bias, idx, out);
}